// Round 5
// baseline (221.677 us; speedup 1.0000x reference)
//
#include <hip/hip_runtime.h>
#include <hip/hip_bf16.h>
#include <math.h>

#define NP 4096      // N
#define DD 128       // D
#define N2 8192      // 2N
#define TINV 10.0f   // 1/temperature
#define SHIFT 10.0f  // fixed lse shift (sim <= 10)
#define C1 14.4269504f       // TINV * log2(e): e = 2^(C1*(acc-1))
#define NGL2 -0.0288539004f  // -GAMMA1 * log2(e), GAMMA1 = 0.02

typedef __attribute__((ext_vector_type(8))) short bf16x8;
typedef __attribute__((ext_vector_type(4))) float f32x4;
typedef __attribute__((ext_vector_type(2))) float f32x2;
typedef __attribute__((ext_vector_type(4))) int i32x4;

// sum over each 16-lane DPP row; result lands in lanes with (lane&15)==0
__device__ __forceinline__ float dpp_red16(float x) {
  x += __int_as_float(__builtin_amdgcn_update_dpp(0, __float_as_int(x), 0x101, 0xF, 0xF, true));
  x += __int_as_float(__builtin_amdgcn_update_dpp(0, __float_as_int(x), 0x102, 0xF, 0xF, true));
  x += __int_as_float(__builtin_amdgcn_update_dpp(0, __float_as_int(x), 0x104, 0xF, 0xF, true));
  x += __int_as_float(__builtin_amdgcn_update_dpp(0, __float_as_int(x), 0x108, 0xF, 0xF, true));
  return x;
}

// ---------------- prep: knorm (blocks 0..2047) || klabel (blocks 2048..6143) ----------------
// rowinfo = (y1, TINV/rs1, y2, TINV/rs2)
__global__ __launch_bounds__(256) void kprep(const float* __restrict__ zi,
                                             const float* __restrict__ zj,
                                             const float* __restrict__ labels,
                                             __hip_bfloat16* __restrict__ Z,
                                             float4* __restrict__ rowinfo,
                                             double* __restrict__ accd,
                                             unsigned int* __restrict__ cnt) {
  int w = threadIdx.x >> 6, lane = threadIdx.x & 63;
  if (blockIdx.x < 2048) {
    // ---- normalize rows -> bf16 ----
    int a = blockIdx.x * 4 + w;
    const float* src = (a < NP) ? (zi + (size_t)a * DD) : (zj + (size_t)(a - NP) * DD);
    float2 v = *(const float2*)(src + lane * 2);
    float ss = v.x * v.x + v.y * v.y;
#pragma unroll
    for (int m = 1; m < 64; m <<= 1) ss += __shfl_xor(ss, m);
    float rn = rsqrtf(ss);
    __hip_bfloat162 o;
    o.x = __float2bfloat16(v.x * rn);
    o.y = __float2bfloat16(v.y * rn);
    *(__hip_bfloat162*)(Z + (size_t)a * DD + lane * 2) = o;
  } else {
    // ---- label row sums ----
    int a = blockIdx.x - 2048;  // 0..NP-1
    if (a == 0 && threadIdx.x == 0) { *accd = 0.0; *cnt = 0u; }  // reset final accum
    float ca = labels[a * 2 + 0], ga = labels[a * 2 + 1];
    float s1 = 0.f, c2 = 0.f;
    for (int m = threadIdx.x; m < NP; m += 256) {
      float2 lm = *(const float2*)(labels + m * 2);
      float dy = ca - lm.x;
      s1 += __builtin_amdgcn_exp2f(dy * dy * NGL2);
      c2 += (ga == lm.y) ? 1.f : 0.f;
    }
#pragma unroll
    for (int m = 1; m < 64; m <<= 1) {
      s1 += __shfl_xor(s1, m);
      c2 += __shfl_xor(c2, m);
    }
    __shared__ float sh[8];
    if (lane == 0) { sh[w] = s1; sh[4 + w] = c2; }
    __syncthreads();
    if (threadIdx.x == 0) {
      s1 = sh[0] + sh[1] + sh[2] + sh[3];
      c2 = sh[4] + sh[5] + sh[6] + sh[7];
      float rs1 = 2.f * s1 - 1.f;         // cont row sum over 8192, diag removed
      float rs2 = (float)NP + c2 - 1.f;   // cat row sum = 4095 + class count
      float4 ri = make_float4(ca, TINV / rs1, ga, TINV / rs2);
      rowinfo[a] = ri;
      rowinfo[a + NP] = ri;
    }
  }
}

// ---------------- main: upper-triangular 128x128 tiles, coalesced float2 partials ----------------
// part[tb] = float2[256]: [0..127] row-side (es, ws), [128..255] col-side. ws includes cont+cat.
// Diag blocks leave col half garbage; kreduce never reads it.
__global__ __launch_bounds__(256, 3) void kmain(const __hip_bfloat16* __restrict__ Zp,
                                                const float4* __restrict__ rowinfo,
                                                float2* __restrict__ part) {
  __shared__ char lds[2 * 128 * 128];  // A half-K panel + B half-K panel, 32 KiB
  char* ldsA = lds;
  char* ldsB = lds + 128 * 128;

  // triangular decode: largest I with I*(129-I)/2 <= tb
  int tb = blockIdx.x;
  int I = (int)((129.0f - sqrtf(16641.0f - 8.0f * (float)tb)) * 0.5f);
  while (I * (129 - I) / 2 > tb) --I;
  while ((I + 1) * (128 - I) / 2 <= tb) ++I;
  int J = I + (tb - I * (129 - I) / 2);
  const bool diag = (I == J);
  const int row0 = I * 128, col0 = J * 128;
  const int t = threadIdx.x;
  const char* gZ = (const char*)Zp;  // [8192][256B]
  const char* ldsBp = diag ? ldsA : ldsB;

  const int lane = t & 63, w = t >> 6;
  const int wr = w >> 1, wc = w & 1;
  const int lrow = lane & 15, lgrp = lane >> 4;

  f32x4 acc[4][4] = {};
#pragma unroll
  for (int kh = 0; kh < 2; ++kh) {  // two K-halves of 64
    if (kh) __syncthreads();
#pragma unroll
    for (int i = 0; i < 4; ++i) {   // stage A half: 1024 x 16B chunks
      int chunk = t + i * 256;
      int r = chunk >> 3;
      int bc = (chunk & 7) << 4;
      int swz = bc ^ ((r & 7) << 4);
      i32x4 va = *(const i32x4*)(gZ + (size_t)(row0 + r) * 256 + kh * 128 + bc);
      *(i32x4*)(ldsA + r * 128 + swz) = va;
    }
    if (!diag) {
#pragma unroll
      for (int i = 0; i < 4; ++i) {
        int chunk = t + i * 256;
        int r = chunk >> 3;
        int bc = (chunk & 7) << 4;
        int swz = bc ^ ((r & 7) << 4);
        i32x4 vb = *(const i32x4*)(gZ + (size_t)(col0 + r) * 256 + kh * 128 + bc);
        *(i32x4*)(ldsB + r * 128 + swz) = vb;
      }
    }
    __syncthreads();
#pragma unroll
    for (int kk = 0; kk < 2; ++kk) {
      int bcol = kk * 64 + (lgrp << 4);
      bf16x8 af[4], bfv[4];
#pragma unroll
      for (int mi = 0; mi < 4; ++mi) {
        int r = wr * 64 + mi * 16 + lrow;
        af[mi] = *(const bf16x8*)(ldsA + r * 128 + (bcol ^ ((r & 7) << 4)));
      }
#pragma unroll
      for (int ni = 0; ni < 4; ++ni) {
        int r = wc * 64 + ni * 16 + lrow;
        bfv[ni] = *(const bf16x8*)(ldsBp + r * 128 + (bcol ^ ((r & 7) << 4)));
      }
#pragma unroll
      for (int mi = 0; mi < 4; ++mi)
#pragma unroll
        for (int ni = 0; ni < 4; ++ni)
          acc[mi][ni] = __builtin_amdgcn_mfma_f32_16x16x32_bf16(af[mi], bfv[ni], acc[mi][ni], 0, 0, 0);
    }
  }

  // epilogue. acc element j of (mi,ni): row a = row0+wr*64+mi*16+lgrp*4+j, col b = col0+wc*64+ni*16+lrow
  float4 rbv[4];
  int bcols[4];
#pragma unroll
  for (int ni = 0; ni < 4; ++ni) {
    int b = col0 + wc * 64 + ni * 16 + lrow;
    rbv[ni] = rowinfo[b];
    bcols[ni] = b;
  }

  float rese[4][4], resw[4][4];  // row partials, valid on lrow==0 lanes
  float2 cv[4];                  // col partials (lanes<16 valid)
  float ec[4] = {0.f, 0.f, 0.f, 0.f}, pc[4] = {0.f, 0.f, 0.f, 0.f}, cc[4] = {0.f, 0.f, 0.f, 0.f};

#pragma unroll
  for (int mi = 0; mi < 4; ++mi) {
    int a0 = row0 + wr * 64 + mi * 16 + lgrp * 4;
#pragma unroll
    for (int j = 0; j < 4; ++j) {
      int a = a0 + j;
      float4 ri = rowinfo[a];
      float es = 0.f, pa = 0.f, ca = 0.f;
#pragma unroll
      for (int ni = 0; ni < 4; ++ni) {
        float v = acc[mi][ni][j];
        float nd = (diag && a == bcols[ni]) ? 0.f : 1.f;  // exclude diagonal element
        float e = __builtin_amdgcn_exp2f(fmaf(v, C1, -C1)) * nd;  // exp(sim-10)
        float dy = ri.x - rbv[ni].x;
        float wu = __builtin_amdgcn_exp2f(dy * dy * NGL2) * nd;   // cont rbf
        float cw = ((ri.z == rbv[ni].z) ? 1.f : 0.5f) * nd;       // cat weight
        es += e;
        ec[ni] += e;
        pa = fmaf(wu, v, pa);
        pc[ni] = fmaf(wu, v, pc[ni]);
        ca = fmaf(cw, v, ca);
        cc[ni] = fmaf(cw, v, cc[ni]);
      }
      // fold both label-weight scales here (uniform across the 16-lane group)
      float wsum = fmaf(pa, ri.y, ca * ri.w);
      rese[mi][j] = dpp_red16(es);
      resw[mi][j] = dpp_red16(wsum);
    }
  }

  if (!diag) {
#pragma unroll
    for (int ni = 0; ni < 4; ++ni) {
      float wcol = fmaf(pc[ni], rbv[ni].y, cc[ni] * rbv[ni].w);
      float e2 = ec[ni] + __shfl_xor(ec[ni], 16);
      e2 += __shfl_xor(e2, 32);
      float w2 = wcol + __shfl_xor(wcol, 16);
      w2 += __shfl_xor(w2, 32);
      cv[ni] = make_float2(e2, w2);
    }
  }

  // combine across waves in LDS (reuse staging buffer), then one coalesced nontemporal write
  float2* lds2 = (float2*)lds;  // [0..127] rows, [128..255] cols
  __syncthreads();              // all ds_reads of staging data complete
  if (wc == 0 && lrow == 0) {
#pragma unroll
    for (int mi = 0; mi < 4; ++mi)
#pragma unroll
      for (int j = 0; j < 4; ++j)
        lds2[wr * 64 + mi * 16 + lgrp * 4 + j] = make_float2(rese[mi][j], resw[mi][j]);
  }
  if (!diag && wr == 0 && lane < 16) {
#pragma unroll
    for (int ni = 0; ni < 4; ++ni) lds2[128 + wc * 64 + ni * 16 + lane] = cv[ni];
  }
  __syncthreads();
  if (wc == 1 && lrow == 0) {
#pragma unroll
    for (int mi = 0; mi < 4; ++mi)
#pragma unroll
      for (int j = 0; j < 4; ++j) {
        int idx = wr * 64 + mi * 16 + lgrp * 4 + j;
        float2 o = lds2[idx];
        o.x += rese[mi][j];
        o.y += resw[mi][j];
        lds2[idx] = o;
      }
  }
  if (!diag && wr == 1 && lane < 16) {
#pragma unroll
    for (int ni = 0; ni < 4; ++ni) {
      int idx = 128 + wc * 64 + ni * 16 + lane;
      float2 o = lds2[idx];
      o.x += cv[ni].x;
      o.y += cv[ni].y;
      lds2[idx] = o;
    }
  }
  __syncthreads();
  {
    float2 o = lds2[t];
    f32x2 v;
    v[0] = o.x;
    v[1] = o.y;
    __builtin_nontemporal_store(v, (f32x2*)(part + (size_t)tb * 256 + t));
  }
}

// ---------------- reduce: fold slots per row-tile, apply log, global double-accumulate ----------------
__global__ __launch_bounds__(128) void kreduce(const float2* __restrict__ part,
                                               double* __restrict__ accd,
                                               unsigned int* __restrict__ cnt,
                                               float* __restrict__ out) {
  int T = blockIdx.x;   // 0..63
  int r = threadIdx.x;  // 0..127
  float es = 0.f, ws = 0.f;
  int tb0 = T * (129 - T) / 2;
  for (int k = 0; k < 64 - T; ++k) {  // row-side: tiles (T, J>=T), contiguous tb
    float2 v = part[(size_t)(tb0 + k) * 256 + r];
    es += v.x;
    ws += v.y;
  }
  for (int I = 0; I < T; ++I) {       // col-side: tiles (I<T, T)
    float2 v = part[(size_t)(I * (129 - I) / 2 + T - I) * 256 + 128 + r];
    es += v.x;
    ws += v.y;
  }
  double val = (double)ws - 2.0 * (double)(SHIFT + __logf(es));
#pragma unroll
  for (int m = 1; m < 64; m <<= 1) val += __shfl_xor(val, m);
  __shared__ double sh[2];
  if ((threadIdx.x & 63) == 0) sh[threadIdx.x >> 6] = val;
  __syncthreads();
  if (threadIdx.x == 0) {
    double bsum = sh[0] + sh[1];
    atomicAdd(accd, bsum);
    __threadfence();
    unsigned int old = atomicAdd(cnt, 1u);
    if (old == 63u) {  // last block finishes the loss
      double tot = atomicAdd(accd, 0.0);  // coherent device-scope read
      out[0] = (float)(-tot / (double)NP);
    }
  }
}

extern "C" void kernel_launch(void* const* d_in, const int* in_sizes, int n_in,
                              void* d_out, int out_size, void* d_ws, size_t ws_size,
                              hipStream_t stream) {
  const float* zi = (const float*)d_in[0];
  const float* zj = (const float*)d_in[1];
  const float* labels = (const float*)d_in[2];
  float* out = (float*)d_out;
  char* ws = (char*)d_ws;

  float4* rowinfo = (float4*)ws;                           // 128 KiB
  double* accd = (double*)(ws + 128 * 1024);               // 8 B
  unsigned int* cnt = (unsigned int*)(ws + 128 * 1024 + 8);
  __hip_bfloat16* Z = (__hip_bfloat16*)(ws + 256 * 1024);  // 2 MiB
  float2* part = (float2*)(ws + 256 * 1024 + 2 * 1024 * 1024);  // 2080*256*8B = 4.16 MiB

  kprep<<<6144, 256, 0, stream>>>(zi, zj, labels, Z, rowinfo, accd, cnt);
  kmain<<<2080, 256, 0, stream>>>(Z, rowinfo, part);
  kreduce<<<64, 128, 0, stream>>>(part, accd, cnt, out);
}

// Round 6
// 216.153 us; speedup vs baseline: 1.0256x; 1.0256x over previous
//
#include <hip/hip_runtime.h>
#include <hip/hip_bf16.h>
#include <math.h>

#define NP 4096      // N
#define DD 128       // D
#define N2 8192      // 2N
#define TINV 10.0f   // 1/temperature
#define SHIFT 10.0f  // fixed lse shift (sim <= 10)
#define C1 14.4269504f       // TINV * log2(e): e = 2^(C1*(acc-1))
#define NGL2 -0.0288539004f  // -GAMMA1 * log2(e), GAMMA1 = 0.02

typedef __attribute__((ext_vector_type(8))) short bf16x8;
typedef __attribute__((ext_vector_type(4))) float f32x4;
typedef __attribute__((ext_vector_type(4))) int i32x4;

// sum over each 16-lane DPP row; result lands in lanes with (lane&15)==0
__device__ __forceinline__ float dpp_red16(float x) {
  x += __int_as_float(__builtin_amdgcn_update_dpp(0, __float_as_int(x), 0x101, 0xF, 0xF, true));
  x += __int_as_float(__builtin_amdgcn_update_dpp(0, __float_as_int(x), 0x102, 0xF, 0xF, true));
  x += __int_as_float(__builtin_amdgcn_update_dpp(0, __float_as_int(x), 0x104, 0xF, 0xF, true));
  x += __int_as_float(__builtin_amdgcn_update_dpp(0, __float_as_int(x), 0x108, 0xF, 0xF, true));
  return x;
}

// ---------------- normalize rows of z_i, z_j -> bf16 Z[2N][128] ----------------
__global__ __launch_bounds__(256) void knorm(const float* __restrict__ zi,
                                             const float* __restrict__ zj,
                                             __hip_bfloat16* __restrict__ Z) {
  int w = threadIdx.x >> 6, lane = threadIdx.x & 63;
  int a = blockIdx.x * 4 + w;
  const float* src = (a < NP) ? (zi + (size_t)a * DD) : (zj + (size_t)(a - NP) * DD);
  float2 v = *(const float2*)(src + lane * 2);
  float ss = v.x * v.x + v.y * v.y;
#pragma unroll
  for (int m = 1; m < 64; m <<= 1) ss += __shfl_xor(ss, m);
  float rn = rsqrtf(ss);
  __hip_bfloat162 o;
  o.x = __float2bfloat16(v.x * rn);
  o.y = __float2bfloat16(v.y * rn);
  *(__hip_bfloat162*)(Z + (size_t)a * DD + lane * 2) = o;
}

// ---------------- label precompute: rowinfo=(y1, TINV/rs1, y2, TINV/rs2) ----------------
__global__ __launch_bounds__(256) void klabel(const float* __restrict__ labels,
                                              float4* __restrict__ rowinfo) {
  int a = blockIdx.x;  // 0..NP-1
  float ca = labels[a * 2 + 0], ga = labels[a * 2 + 1];
  float s1 = 0.f, c2 = 0.f;
  for (int m = threadIdx.x; m < NP; m += 256) {
    float2 lm = *(const float2*)(labels + m * 2);
    float dy = ca - lm.x;
    s1 += __builtin_amdgcn_exp2f(dy * dy * NGL2);
    c2 += (ga == lm.y) ? 1.f : 0.f;
  }
#pragma unroll
  for (int m = 1; m < 64; m <<= 1) {
    s1 += __shfl_xor(s1, m);
    c2 += __shfl_xor(c2, m);
  }
  __shared__ float sh[8];
  int w = threadIdx.x >> 6, lane = threadIdx.x & 63;
  if (lane == 0) { sh[w] = s1; sh[4 + w] = c2; }
  __syncthreads();
  if (threadIdx.x == 0) {
    s1 = sh[0] + sh[1] + sh[2] + sh[3];
    c2 = sh[4] + sh[5] + sh[6] + sh[7];
    float rs1 = 2.f * s1 - 1.f;         // cont row sum over 8192, diag removed
    float rs2 = (float)NP + c2 - 1.f;   // cat row sum = 4095 + class count
    float4 ri = make_float4(ca, TINV / rs1, ga, TINV / rs2);
    rowinfo[a] = ri;
    rowinfo[a + NP] = ri;
  }
}

// ---------------- main: upper-triangular 128x128 tiles, coalesced float2 partials ----------------
// part[tb] = float2[256]: [0..127] row-side (es, ws), [128..255] col-side. ws = cont + cat terms.
// Diag blocks leave col half garbage; kreduce never reads it.
__global__ __launch_bounds__(256, 3) void kmain(const __hip_bfloat16* __restrict__ Zp,
                                                const float4* __restrict__ rowinfo,
                                                float2* __restrict__ part) {
  __shared__ char lds[2 * 128 * 128];  // A half-K panel + B half-K panel, 32 KiB
  char* ldsA = lds;
  char* ldsB = lds + 128 * 128;

  // triangular decode: largest I with I*(129-I)/2 <= tb
  int tb = blockIdx.x;
  int I = (int)((129.0f - sqrtf(16641.0f - 8.0f * (float)tb)) * 0.5f);
  while (I * (129 - I) / 2 > tb) --I;
  while ((I + 1) * (128 - I) / 2 <= tb) ++I;
  int J = I + (tb - I * (129 - I) / 2);
  const bool diag = (I == J);
  const int row0 = I * 128, col0 = J * 128;
  const int t = threadIdx.x;
  const char* gZ = (const char*)Zp;  // [8192][256B]
  const char* ldsBp = diag ? ldsA : ldsB;

  const int lane = t & 63, w = t >> 6;
  const int wr = w >> 1, wc = w & 1;
  const int lrow = lane & 15, lgrp = lane >> 4;

  f32x4 acc[4][4] = {};
#pragma unroll
  for (int kh = 0; kh < 2; ++kh) {  // two K-halves of 64
    if (kh) __syncthreads();
#pragma unroll
    for (int i = 0; i < 4; ++i) {   // stage A half: 1024 x 16B chunks
      int chunk = t + i * 256;
      int r = chunk >> 3;
      int bc = (chunk & 7) << 4;
      int swz = bc ^ ((r & 7) << 4);
      i32x4 va = *(const i32x4*)(gZ + (size_t)(row0 + r) * 256 + kh * 128 + bc);
      *(i32x4*)(ldsA + r * 128 + swz) = va;
    }
    if (!diag) {
#pragma unroll
      for (int i = 0; i < 4; ++i) {
        int chunk = t + i * 256;
        int r = chunk >> 3;
        int bc = (chunk & 7) << 4;
        int swz = bc ^ ((r & 7) << 4);
        i32x4 vb = *(const i32x4*)(gZ + (size_t)(col0 + r) * 256 + kh * 128 + bc);
        *(i32x4*)(ldsB + r * 128 + swz) = vb;
      }
    }
    __syncthreads();
#pragma unroll
    for (int kk = 0; kk < 2; ++kk) {
      int bcol = kk * 64 + (lgrp << 4);
      bf16x8 af[4], bfv[4];
#pragma unroll
      for (int mi = 0; mi < 4; ++mi) {
        int r = wr * 64 + mi * 16 + lrow;
        af[mi] = *(const bf16x8*)(ldsA + r * 128 + (bcol ^ ((r & 7) << 4)));
      }
#pragma unroll
      for (int ni = 0; ni < 4; ++ni) {
        int r = wc * 64 + ni * 16 + lrow;
        bfv[ni] = *(const bf16x8*)(ldsBp + r * 128 + (bcol ^ ((r & 7) << 4)));
      }
#pragma unroll
      for (int mi = 0; mi < 4; ++mi)
#pragma unroll
        for (int ni = 0; ni < 4; ++ni)
          acc[mi][ni] = __builtin_amdgcn_mfma_f32_16x16x32_bf16(af[mi], bfv[ni], acc[mi][ni], 0, 0, 0);
    }
  }

  // epilogue. acc element j of (mi,ni): row a = row0+wr*64+mi*16+lgrp*4+j, col b = col0+wc*64+ni*16+lrow
  float4 rbv[4];
  int bcols[4];
#pragma unroll
  for (int ni = 0; ni < 4; ++ni) {
    int b = col0 + wc * 64 + ni * 16 + lrow;
    rbv[ni] = rowinfo[b];
    bcols[ni] = b;
  }

  float rese[4][4], resw[4][4];  // row partials, valid on lrow==0 lanes
  float2 cv[4];                  // col partials (lanes<16 valid)
  float ec[4] = {0.f, 0.f, 0.f, 0.f}, pc[4] = {0.f, 0.f, 0.f, 0.f}, cc[4] = {0.f, 0.f, 0.f, 0.f};

#pragma unroll
  for (int mi = 0; mi < 4; ++mi) {
    int a0 = row0 + wr * 64 + mi * 16 + lgrp * 4;
#pragma unroll
    for (int j = 0; j < 4; ++j) {
      int a = a0 + j;
      float4 ri = rowinfo[a];
      float es = 0.f, pa = 0.f, ca = 0.f;
#pragma unroll
      for (int ni = 0; ni < 4; ++ni) {
        float v = acc[mi][ni][j];
        float nd = (diag && a == bcols[ni]) ? 0.f : 1.f;  // exclude diagonal element
        float e = __builtin_amdgcn_exp2f(fmaf(v, C1, -C1)) * nd;  // exp(sim-10)
        float dy = ri.x - rbv[ni].x;
        float wu = __builtin_amdgcn_exp2f(dy * dy * NGL2) * nd;   // cont rbf
        float cw = ((ri.z == rbv[ni].z) ? 1.f : 0.5f) * nd;       // cat weight
        es += e;
        ec[ni] += e;
        pa = fmaf(wu, v, pa);
        pc[ni] = fmaf(wu, v, pc[ni]);
        ca = fmaf(cw, v, ca);
        cc[ni] = fmaf(cw, v, cc[ni]);
      }
      // fold both label-weight scales here (uniform across the 16-lane group)
      float wsum = fmaf(pa, ri.y, ca * ri.w);
      rese[mi][j] = dpp_red16(es);
      resw[mi][j] = dpp_red16(wsum);
    }
  }

  if (!diag) {
#pragma unroll
    for (int ni = 0; ni < 4; ++ni) {
      float wcol = fmaf(pc[ni], rbv[ni].y, cc[ni] * rbv[ni].w);
      float e2 = ec[ni] + __shfl_xor(ec[ni], 16);
      e2 += __shfl_xor(e2, 32);
      float w2 = wcol + __shfl_xor(wcol, 16);
      w2 += __shfl_xor(w2, 32);
      cv[ni] = make_float2(e2, w2);
    }
  }

  // combine across waves in LDS (reuse staging buffer), then one coalesced write
  float2* lds2 = (float2*)lds;  // [0..127] rows, [128..255] cols
  __syncthreads();              // all ds_reads of staging data complete
  if (wc == 0 && lrow == 0) {
#pragma unroll
    for (int mi = 0; mi < 4; ++mi)
#pragma unroll
      for (int j = 0; j < 4; ++j)
        lds2[wr * 64 + mi * 16 + lgrp * 4 + j] = make_float2(rese[mi][j], resw[mi][j]);
  }
  if (!diag && wr == 0 && lane < 16) {
#pragma unroll
    for (int ni = 0; ni < 4; ++ni) lds2[128 + wc * 64 + ni * 16 + lane] = cv[ni];
  }
  __syncthreads();
  if (wc == 1 && lrow == 0) {
#pragma unroll
    for (int mi = 0; mi < 4; ++mi)
#pragma unroll
      for (int j = 0; j < 4; ++j) {
        int idx = wr * 64 + mi * 16 + lgrp * 4 + j;
        float2 o = lds2[idx];
        o.x += rese[mi][j];
        o.y += resw[mi][j];
        lds2[idx] = o;
      }
  }
  if (!diag && wr == 1 && lane < 16) {
#pragma unroll
    for (int ni = 0; ni < 4; ++ni) {
      int idx = 128 + wc * 64 + ni * 16 + lane;
      float2 o = lds2[idx];
      o.x += cv[ni].x;
      o.y += cv[ni].y;
      lds2[idx] = o;
    }
  }
  __syncthreads();
  part[(size_t)tb * 256 + t] = lds2[t];
}

// ---------------- reduce per row-tile: fold slots, apply log ----------------
__global__ __launch_bounds__(128) void kreduce(const float2* __restrict__ part,
                                               double* __restrict__ tilesum) {
  int T = blockIdx.x;   // 0..63
  int r = threadIdx.x;  // 0..127
  float es = 0.f, ws = 0.f;
  int tb0 = T * (129 - T) / 2;
  for (int k = 0; k < 64 - T; ++k) {  // row-side: tiles (T, J>=T), contiguous tb
    float2 v = part[(size_t)(tb0 + k) * 256 + r];
    es += v.x;
    ws += v.y;
  }
  for (int I = 0; I < T; ++I) {       // col-side: tiles (I<T, T)
    float2 v = part[(size_t)(I * (129 - I) / 2 + T - I) * 256 + 128 + r];
    es += v.x;
    ws += v.y;
  }
  double val = (double)ws - 2.0 * (double)(SHIFT + __logf(es));
#pragma unroll
  for (int m = 1; m < 64; m <<= 1) val += __shfl_xor(val, m);
  __shared__ double sh[2];
  if ((threadIdx.x & 63) == 0) sh[threadIdx.x >> 6] = val;
  __syncthreads();
  if (threadIdx.x == 0) tilesum[T] = sh[0] + sh[1];
}

// ---------------- final: loss = -(1/N) * sum of tile sums ----------------
__global__ __launch_bounds__(64) void kfinal(const double* __restrict__ tilesum,
                                             float* __restrict__ out) {
  double v = tilesum[threadIdx.x];
#pragma unroll
  for (int m = 1; m < 64; m <<= 1) v += __shfl_xor(v, m);
  if (threadIdx.x == 0) out[0] = (float)(-v / (double)NP);
}

extern "C" void kernel_launch(void* const* d_in, const int* in_sizes, int n_in,
                              void* d_out, int out_size, void* d_ws, size_t ws_size,
                              hipStream_t stream) {
  const float* zi = (const float*)d_in[0];
  const float* zj = (const float*)d_in[1];
  const float* labels = (const float*)d_in[2];
  float* out = (float*)d_out;
  char* ws = (char*)d_ws;

  float4* rowinfo = (float4*)ws;                           // 128 KiB
  double* tilesum = (double*)(ws + 128 * 1024);            // 512 B
  __hip_bfloat16* Z = (__hip_bfloat16*)(ws + 256 * 1024);  // 2 MiB
  float2* part = (float2*)(ws + 256 * 1024 + 2 * 1024 * 1024);  // 2080*256*8B = 4.16 MiB

  knorm<<<2048, 256, 0, stream>>>(zi, zj, Z);
  klabel<<<4096, 256, 0, stream>>>(labels, rowinfo);
  kmain<<<2080, 256, 0, stream>>>(Z, rowinfo, part);
  kreduce<<<64, 128, 0, stream>>>(part, tilesum);
  kfinal<<<1, 64, 0, stream>>>(tilesum, out);
}

// Round 7
// 100.114 us; speedup vs baseline: 2.2142x; 2.1591x over previous
//
#include <hip/hip_runtime.h>
#include <hip/hip_bf16.h>
#include <math.h>

#define NP 4096      // N
#define DD 128       // D
#define N2 8192      // 2N
#define TINV 10.0f   // 1/temperature
#define SHIFT 10.0f  // fixed lse shift (sim <= 10)
#define C1 14.4269504f       // TINV * log2(e): e = 2^(C1*(acc-1))
#define NGL2 -0.0288539004f  // -GAMMA1 * log2(e), GAMMA1 = 0.02

typedef __attribute__((ext_vector_type(8))) short bf16x8;
typedef __attribute__((ext_vector_type(4))) float f32x4;
typedef __attribute__((ext_vector_type(4))) int i32x4;

// sum over each 16-lane DPP row; result lands in lanes with (lane&15)==0
__device__ __forceinline__ float dpp_red16(float x) {
  x += __int_as_float(__builtin_amdgcn_update_dpp(0, __float_as_int(x), 0x101, 0xF, 0xF, true));
  x += __int_as_float(__builtin_amdgcn_update_dpp(0, __float_as_int(x), 0x102, 0xF, 0xF, true));
  x += __int_as_float(__builtin_amdgcn_update_dpp(0, __float_as_int(x), 0x104, 0xF, 0xF, true));
  x += __int_as_float(__builtin_amdgcn_update_dpp(0, __float_as_int(x), 0x108, 0xF, 0xF, true));
  return x;
}

// ---------------- normalize rows of z_i, z_j -> bf16 Z[2N][128] ----------------
__global__ __launch_bounds__(256) void knorm(const float* __restrict__ zi,
                                             const float* __restrict__ zj,
                                             __hip_bfloat16* __restrict__ Z) {
  int w = threadIdx.x >> 6, lane = threadIdx.x & 63;
  int a = blockIdx.x * 4 + w;
  const float* src = (a < NP) ? (zi + (size_t)a * DD) : (zj + (size_t)(a - NP) * DD);
  float2 v = *(const float2*)(src + lane * 2);
  float ss = v.x * v.x + v.y * v.y;
#pragma unroll
  for (int m = 1; m < 64; m <<= 1) ss += __shfl_xor(ss, m);
  float rn = rsqrtf(ss);
  __hip_bfloat162 o;
  o.x = __float2bfloat16(v.x * rn);
  o.y = __float2bfloat16(v.y * rn);
  *(__hip_bfloat162*)(Z + (size_t)a * DD + lane * 2) = o;
}

// ---------------- label precompute: rowinfo=(y1, TINV/rs1, y2, TINV/rs2) ----------------
__global__ __launch_bounds__(256) void klabel(const float* __restrict__ labels,
                                              float4* __restrict__ rowinfo) {
  int a = blockIdx.x;  // 0..NP-1
  float ca = labels[a * 2 + 0], ga = labels[a * 2 + 1];
  float s1 = 0.f, c2 = 0.f;
  for (int m = threadIdx.x; m < NP; m += 256) {
    float2 lm = *(const float2*)(labels + m * 2);
    float dy = ca - lm.x;
    s1 += __builtin_amdgcn_exp2f(dy * dy * NGL2);
    c2 += (ga == lm.y) ? 1.f : 0.f;
  }
#pragma unroll
  for (int m = 1; m < 64; m <<= 1) {
    s1 += __shfl_xor(s1, m);
    c2 += __shfl_xor(c2, m);
  }
  __shared__ float sh[8];
  int w = threadIdx.x >> 6, lane = threadIdx.x & 63;
  if (lane == 0) { sh[w] = s1; sh[4 + w] = c2; }
  __syncthreads();
  if (threadIdx.x == 0) {
    s1 = sh[0] + sh[1] + sh[2] + sh[3];
    c2 = sh[4] + sh[5] + sh[6] + sh[7];
    float rs1 = 2.f * s1 - 1.f;         // cont row sum over 8192, diag removed
    float rs2 = (float)NP + c2 - 1.f;   // cat row sum = 4095 + class count
    float4 ri = make_float4(ca, TINV / rs1, ga, TINV / rs2);
    rowinfo[a] = ri;
    rowinfo[a + NP] = ri;
  }
}

// ---------------- main: upper-triangular 128x128 tiles, LDS-atomic partials ----------------
// part[tb] = float2[256]: [0..127] row-side (es, ws), [128..255] col-side. ws = cont + cat.
__global__ __launch_bounds__(256) void kmain(const __hip_bfloat16* __restrict__ Zp,
                                             const float4* __restrict__ rowinfo,
                                             float2* __restrict__ part) {
  __shared__ char lds[2 * 128 * 128];  // A half-K panel + B half-K panel, 32 KiB
  char* ldsA = lds;
  char* ldsB = lds + 128 * 128;

  // bijective XCD swizzle (2080 % 8 == 0): each XCD gets 260 consecutive tiles
  int tb = (blockIdx.x & 7) * 260 + (blockIdx.x >> 3);

  // triangular decode: largest I with I*(129-I)/2 <= tb
  int I = (int)((129.0f - sqrtf(16641.0f - 8.0f * (float)tb)) * 0.5f);
  while (I * (129 - I) / 2 > tb) --I;
  while ((I + 1) * (128 - I) / 2 <= tb) ++I;
  int J = I + (tb - I * (129 - I) / 2);
  const bool diag = (I == J);
  const int row0 = I * 128, col0 = J * 128;
  const int t = threadIdx.x;
  const char* gZ = (const char*)Zp;  // [8192][256B]
  const char* ldsBp = diag ? ldsA : ldsB;

  const int lane = t & 63, w = t >> 6;
  const int wr = w >> 1, wc = w & 1;
  const int lrow = lane & 15, lgrp = lane >> 4;

  f32x4 acc[4][4] = {};
#pragma unroll
  for (int kh = 0; kh < 2; ++kh) {  // two K-halves of 64
    if (kh) __syncthreads();
#pragma unroll
    for (int i = 0; i < 4; ++i) {   // stage A half: 1024 x 16B chunks
      int chunk = t + i * 256;
      int r = chunk >> 3;
      int bc = (chunk & 7) << 4;
      int swz = bc ^ ((r & 7) << 4);
      i32x4 va = *(const i32x4*)(gZ + (size_t)(row0 + r) * 256 + kh * 128 + bc);
      *(i32x4*)(ldsA + r * 128 + swz) = va;
    }
    if (!diag) {
#pragma unroll
      for (int i = 0; i < 4; ++i) {
        int chunk = t + i * 256;
        int r = chunk >> 3;
        int bc = (chunk & 7) << 4;
        int swz = bc ^ ((r & 7) << 4);
        i32x4 vb = *(const i32x4*)(gZ + (size_t)(col0 + r) * 256 + kh * 128 + bc);
        *(i32x4*)(ldsB + r * 128 + swz) = vb;
      }
    }
    __syncthreads();
#pragma unroll
    for (int kk = 0; kk < 2; ++kk) {
      int bcol = kk * 64 + (lgrp << 4);
      bf16x8 af[4], bfv[4];
#pragma unroll
      for (int mi = 0; mi < 4; ++mi) {
        int r = wr * 64 + mi * 16 + lrow;
        af[mi] = *(const bf16x8*)(ldsA + r * 128 + (bcol ^ ((r & 7) << 4)));
      }
#pragma unroll
      for (int ni = 0; ni < 4; ++ni) {
        int r = wc * 64 + ni * 16 + lrow;
        bfv[ni] = *(const bf16x8*)(ldsBp + r * 128 + (bcol ^ ((r & 7) << 4)));
      }
#pragma unroll
      for (int mi = 0; mi < 4; ++mi)
#pragma unroll
        for (int ni = 0; ni < 4; ++ni)
          acc[mi][ni] = __builtin_amdgcn_mfma_f32_16x16x32_bf16(af[mi], bfv[ni], acc[mi][ni], 0, 0, 0);
    }
  }

  // ---- epilogue: accumulate straight into LDS slots (no register result arrays) ----
  float4 rbv[4];
  int bcols[4];
#pragma unroll
  for (int ni = 0; ni < 4; ++ni) {
    int b = col0 + wc * 64 + ni * 16 + lrow;
    rbv[ni] = rowinfo[b];
    bcols[ni] = b;
  }

  __syncthreads();  // all ds_reads of staging data done; safe to repurpose LDS
  float* lacc = (float*)lds;  // float[512]: [2*r] es, [2*r+1] ws; rows 0..127, cols 128..255
  lacc[t] = 0.f;
  lacc[t + 256] = 0.f;
  __syncthreads();

  float ec[4] = {0.f, 0.f, 0.f, 0.f}, pc[4] = {0.f, 0.f, 0.f, 0.f}, cc[4] = {0.f, 0.f, 0.f, 0.f};

#pragma unroll
  for (int mi = 0; mi < 4; ++mi) {
    int a0 = row0 + wr * 64 + mi * 16 + lgrp * 4;
#pragma unroll
    for (int j = 0; j < 4; ++j) {
      int a = a0 + j;
      float4 ri = rowinfo[a];
      float es = 0.f, pa = 0.f, ca = 0.f;
#pragma unroll
      for (int ni = 0; ni < 4; ++ni) {
        float v = acc[mi][ni][j];
        float nd = (diag && a == bcols[ni]) ? 0.f : 1.f;  // exclude diagonal element
        float e = __builtin_amdgcn_exp2f(fmaf(v, C1, -C1)) * nd;  // exp(sim-10)
        float dy = ri.x - rbv[ni].x;
        float wu = __builtin_amdgcn_exp2f(dy * dy * NGL2) * nd;   // cont rbf
        float cw = ((ri.z == rbv[ni].z) ? 1.f : 0.5f) * nd;       // cat weight
        es += e;
        ec[ni] += e;
        pa = fmaf(wu, v, pa);
        pc[ni] = fmaf(wu, v, pc[ni]);
        ca = fmaf(cw, v, ca);
        cc[ni] = fmaf(cw, v, cc[ni]);
      }
      float wsum = fmaf(pa, ri.y, ca * ri.w);  // fold scales (uniform in 16-lane group)
      es = dpp_red16(es);
      wsum = dpp_red16(wsum);
      if (lrow == 0) {
        int idx = wr * 64 + mi * 16 + lgrp * 4 + j;  // local row 0..127
        atomicAdd(&lacc[2 * idx], es);       // ds_add_f32, <=2 colliders
        atomicAdd(&lacc[2 * idx + 1], wsum);
      }
    }
  }

  if (!diag) {
#pragma unroll
    for (int ni = 0; ni < 4; ++ni) {
      float wcol = fmaf(pc[ni], rbv[ni].y, cc[ni] * rbv[ni].w);
      float e2 = ec[ni] + __shfl_xor(ec[ni], 16);
      e2 += __shfl_xor(e2, 32);
      float w2 = wcol + __shfl_xor(wcol, 16);
      w2 += __shfl_xor(w2, 32);
      if (lane < 16) {
        int idx = 128 + wc * 64 + ni * 16 + lane;  // local col slot
        atomicAdd(&lacc[2 * idx], e2);
        atomicAdd(&lacc[2 * idx + 1], w2);
      }
    }
  }

  __syncthreads();
  ((float2*)part)[(size_t)tb * 256 + t] = ((float2*)lacc)[t];
}

// ---------------- reduce per row-tile: fold slots, apply log ----------------
__global__ __launch_bounds__(128) void kreduce(const float2* __restrict__ part,
                                               double* __restrict__ tilesum) {
  int T = blockIdx.x;   // 0..63
  int r = threadIdx.x;  // 0..127
  float es = 0.f, ws = 0.f;
  int tb0 = T * (129 - T) / 2;
  for (int k = 0; k < 64 - T; ++k) {  // row-side: tiles (T, J>=T), contiguous tb
    float2 v = part[(size_t)(tb0 + k) * 256 + r];
    es += v.x;
    ws += v.y;
  }
  for (int I = 0; I < T; ++I) {       // col-side: tiles (I<T, T)
    float2 v = part[(size_t)(I * (129 - I) / 2 + T - I) * 256 + 128 + r];
    es += v.x;
    ws += v.y;
  }
  double val = (double)ws - 2.0 * (double)(SHIFT + __logf(es));
#pragma unroll
  for (int m = 1; m < 64; m <<= 1) val += __shfl_xor(val, m);
  __shared__ double sh[2];
  if ((threadIdx.x & 63) == 0) sh[threadIdx.x >> 6] = val;
  __syncthreads();
  if (threadIdx.x == 0) tilesum[T] = sh[0] + sh[1];
}

// ---------------- final: loss = -(1/N) * sum of tile sums ----------------
__global__ __launch_bounds__(64) void kfinal(const double* __restrict__ tilesum,
                                             float* __restrict__ out) {
  double v = tilesum[threadIdx.x];
#pragma unroll
  for (int m = 1; m < 64; m <<= 1) v += __shfl_xor(v, m);
  if (threadIdx.x == 0) out[0] = (float)(-v / (double)NP);
}

extern "C" void kernel_launch(void* const* d_in, const int* in_sizes, int n_in,
                              void* d_out, int out_size, void* d_ws, size_t ws_size,
                              hipStream_t stream) {
  const float* zi = (const float*)d_in[0];
  const float* zj = (const float*)d_in[1];
  const float* labels = (const float*)d_in[2];
  float* out = (float*)d_out;
  char* ws = (char*)d_ws;

  float4* rowinfo = (float4*)ws;                           // 128 KiB
  double* tilesum = (double*)(ws + 128 * 1024);            // 512 B
  __hip_bfloat16* Z = (__hip_bfloat16*)(ws + 256 * 1024);  // 2 MiB
  float2* part = (float2*)(ws + 256 * 1024 + 2 * 1024 * 1024);  // 2080*256*8B = 4.16 MiB

  knorm<<<2048, 256, 0, stream>>>(zi, zj, Z);
  klabel<<<4096, 256, 0, stream>>>(labels, rowinfo);
  kmain<<<2080, 256, 0, stream>>>(Z, rowinfo, part);
  kreduce<<<64, 128, 0, stream>>>(part, tilesum);
  kfinal<<<1, 64, 0, stream>>>(tilesum, out);
}